// Round 7
// baseline (95.144 us; speedup 1.0000x reference)
//
#include <hip/hip_runtime.h>

// GAT dense attention, two kernels (kernel boundary = the inter-phase barrier;
// in-kernel device-scope fences measured catastrophic in round 2: ~85us stall).
// Softmax numerator factorized rank-1:
//   p_ij = exp(max(z, 0.2z)), z = s_i + t_j  ->  max(alpha_i*E_j, beta_i*F_j)
// Shapes: B=4, N=2048, F_in=128, H=4, d=32. out[b][n][h*32+d] fp32.
//
// k1: round-5 hardware-verified, byte-identical (ONE LDS allocation, manual
// hi/lo offsets — round-3 lesson: never assume __shared__ arrays adjacent).
// k3: SAME 512-block x 64-row decomposition as the verified version, widened
// to 512 threads (8 waves): wave = (16-row group) x (j-half). 2 blocks/CU x
// 8 waves = 16 waves/CU (was 8). The 1024-block 32-row variant is retired
// (0-for-2: r3 numeric w/ k1 confound, r6 core dump).

#define LOG2E 1.4426950408889634f
constexpr int Nn = 2048, Fin = 128, Dd = 32;

typedef _Float16 half8 __attribute__((ext_vector_type(8)));
typedef _Float16 half4v __attribute__((ext_vector_type(4)));
typedef _Float16 half2v __attribute__((ext_vector_type(2)));
typedef float f32x4 __attribute__((ext_vector_type(4)));

union H8 { half2v h2[4]; half8 h8; };

// ---------------- Kernel 1: Wh = x @ W (f16 hi/lo 3-MFMA), s, t, whT --------
// 512 blocks (16 bh x 32 tiles of 64 rows) x 256 thr; wave = one 16-row M-tile.
// W pre-split hi/lo into one LDS buffer (coalesced, once per block), replacing
// 64 strided scalar global loads + ~200 cvt VALU per lane in the MFMA loop.
__global__ __launch_bounds__(256) void k1_wh(
    const float* __restrict__ x, const float* __restrict__ W,
    const float* __restrict__ a, _Float16* __restrict__ whT,
    float* __restrict__ sArr, float* __restrict__ tArr) {
  constexpr int KLD = 136;  // halves; mult of 8 -> 16B-aligned b128 reads
  __shared__ __align__(16) _Float16 Wlds[2 * 32 * KLD];  // [hi|lo][d][k]
  _Float16* BhL = Wlds;            // explicit offsets within ONE allocation
  _Float16* BlL = Wlds + 32 * KLD;

  int blk = blockIdx.x;
  int bh = blk >> 5, tile = blk & 31;
  int b = bh >> 2, h = bh & 3;
  int tid = threadIdx.x, w = tid >> 6, lane = tid & 63;
  int q = lane >> 4, m = lane & 15;
  int rowbase = tile * 64 + w * 16;

  const float* Wq = W + h * Fin * Dd;
  {
    // thread: k = tid>>1 (0..127), d = (tid&1)*16 .. +15. Fully coalesced.
    int k = tid >> 1, dbase = (tid & 1) * 16;
    const float* wp = Wq + k * Dd + dbase;
    float4 w0 = *(const float4*)(wp);
    float4 w1 = *(const float4*)(wp + 4);
    float4 w2 = *(const float4*)(wp + 8);
    float4 w3 = *(const float4*)(wp + 12);
    float wv[16] = {w0.x, w0.y, w0.z, w0.w, w1.x, w1.y, w1.z, w1.w,
                    w2.x, w2.y, w2.z, w2.w, w3.x, w3.y, w3.z, w3.w};
#pragma unroll
    for (int u = 0; u < 16; ++u) {
      _Float16 hi = (_Float16)wv[u];
      BhL[(dbase + u) * KLD + k] = hi;
      BlL[(dbase + u) * KLD + k] = (_Float16)(wv[u] - (float)hi);
    }
  }
  __syncthreads();

  const float* xb = x + (size_t)(b * Nn + rowbase + m) * Fin;
  f32x4 acc[2];
  acc[0] = (f32x4){0.f, 0.f, 0.f, 0.f};
  acc[1] = (f32x4){0.f, 0.f, 0.f, 0.f};

#pragma unroll
  for (int kt = 0; kt < 4; ++kt) {
    float4 x0 = *(const float4*)(xb + kt * 32 + q * 8);
    float4 x1 = *(const float4*)(xb + kt * 32 + q * 8 + 4);
    float xv[8] = {x0.x, x0.y, x0.z, x0.w, x1.x, x1.y, x1.z, x1.w};
    half8 Ah, Al;
#pragma unroll
    for (int j = 0; j < 8; ++j) {
      _Float16 hi = (_Float16)xv[j];
      Ah[j] = hi;
      Al[j] = (_Float16)(xv[j] - (float)hi);
    }
#pragma unroll
    for (int nt = 0; nt < 2; ++nt) {
      int off = (nt * 16 + m) * KLD + kt * 32 + q * 8;
      half8 Bh = *(const half8*)&BhL[off];
      half8 Bl = *(const half8*)&BlL[off];
      acc[nt] = __builtin_amdgcn_mfma_f32_16x16x32_f16(Ah, Bh, acc[nt], 0, 0, 0);
      acc[nt] = __builtin_amdgcn_mfma_f32_16x16x32_f16(Al, Bh, acc[nt], 0, 0, 0);
      acc[nt] = __builtin_amdgcn_mfma_f32_16x16x32_f16(Ah, Bl, acc[nt], 0, 0, 0);
    }
  }

  // C layout: lane(q,m) -> rows rowbase+q*4+r, col d = nt*16+m.
#pragma unroll
  for (int nt = 0; nt < 2; ++nt) {
    int d = nt * 16 + m;
    half4v h4;
#pragma unroll
    for (int r = 0; r < 4; ++r) h4[r] = (_Float16)acc[nt][r];
    *(half4v*)(whT + (size_t)(bh * Dd + d) * Nn + rowbase + q * 4) = h4;
  }

  const float* ah = a + h * 2 * Dd;
  float a1m0 = ah[m], a1m1 = ah[16 + m];
  float a2m0 = ah[Dd + m], a2m1 = ah[Dd + 16 + m];
#pragma unroll
  for (int r = 0; r < 4; ++r) {
    float ps = acc[0][r] * a1m0 + acc[1][r] * a1m1;
    float pt = acc[0][r] * a2m0 + acc[1][r] * a2m1;
#pragma unroll
    for (int off = 1; off < 16; off <<= 1) {
      ps += __shfl_xor(ps, off);
      pt += __shfl_xor(pt, off);
    }
    if (m == 0) {
      sArr[bh * Nn + rowbase + q * 4 + r] = ps;
      tArr[bh * Nn + rowbase + q * 4 + r] = pt;
    }
  }
}

// ---------------- Kernel 3: h = softmax(e) @ Wh via f16 MFMA ----------------
// 512 blocks (16 bh x 32 tiles of 64 rows) x 512 thr = 8 waves.
// Wave w: row-group wrg = w&3 (16 rows), j-half wj = w>>2 (1024 j, 32 steps).
// 2 blocks/CU x 8 waves = 16 waves/CU. 17.4 KB LDS. launch_bounds(512,4)
// caps VGPR at 128 (main loop needs ~60). Prefetch + MFMA-den as verified.
__global__ __launch_bounds__(512, 4) void k3_attn(
    const _Float16* __restrict__ whT, const float* __restrict__ sArr,
    const float* __restrict__ tArr, float* __restrict__ out) {
  __shared__ float smem[4352];               // 17.4 KB union
  _Float16* Ef = (_Float16*)smem;            // [2048] f16 (floats 0..1023)
  _Float16* Ff = (_Float16*)(smem + 1024);   // [2048] f16 (floats 1024..2047)
  float* red = smem + 2048;                  // [8] wave-max scratch

  int blk = blockIdx.x;
  int bh = blk >> 5, tile = blk & 31;
  int b = bh >> 2, h = bh & 3;
  int tid = threadIdx.x, w = tid >> 6, lane = tid & 63;
  int q = lane >> 4, m = lane & 15;
  int wrg = w & 3, wj = w >> 2;

  // ---- prologue: T via wave-shuffle + 1 barrier, then E/F tables ----
  float tv[4];
  float mx = -1e30f;
#pragma unroll
  for (int k = 0; k < 4; ++k) {
    tv[k] = tArr[bh * Nn + tid + k * 512];
    mx = fmaxf(mx, tv[k]);
  }
#pragma unroll
  for (int off = 32; off > 0; off >>= 1) mx = fmaxf(mx, __shfl_xor(mx, off));
  if (lane == 0) red[w] = mx;
  __syncthreads();
  float T = fmaxf(fmaxf(fmaxf(red[0], red[1]), fmaxf(red[2], red[3])),
                  fmaxf(fmaxf(red[4], red[5]), fmaxf(red[6], red[7])));
#pragma unroll
  for (int k = 0; k < 4; ++k) {
    float dt = tv[k] - T;  // <= 0
    Ef[tid + k * 512] = (_Float16)__builtin_amdgcn_exp2f(LOG2E * dt);
    Ff[tid + k * 512] = (_Float16)__builtin_amdgcn_exp2f(0.2f * LOG2E * dt);
  }

  // per-row alpha/beta for this wave's 16 rows (replicated f16 pairs)
  half2v aa, bb;
  {
    float es = sArr[bh * Nn + tile * 64 + wrg * 16 + m] + T;
    float al = __builtin_amdgcn_exp2f(0.8f * LOG2E * fminf(es, 0.f));
    float be = __builtin_amdgcn_exp2f(-0.8f * LOG2E * fmaxf(es, 0.f));
    _Float16 ah_ = (_Float16)al, bh_ = (_Float16)be;
    aa = (half2v){ah_, ah_};
    bb = (half2v){bh_, bh_};
  }
  __syncthreads();  // E/F visible to all waves

  f32x4 acc0 = (f32x4){0.f, 0.f, 0.f, 0.f};
  f32x4 acc1 = (f32x4){0.f, 0.f, 0.f, 0.f};
  f32x4 accd = (f32x4){0.f, 0.f, 0.f, 0.f};
  // den via MFMA: B fragment = ones in column 0 (lanes m==0), zero elsewhere.
  half8 bden;
  {
    _Float16 v = (_Float16)((m == 0) ? 1.f : 0.f);
#pragma unroll
    for (int j = 0; j < 8; ++j) bden[j] = v;
  }

  const _Float16* wb = whT + (size_t)bh * Dd * Nn;
  const int jb0 = wj * 1024;

  // ---- main loop: 32 steps of 32 j, 1-step prefetch, no barriers/exp ----
  half8 B0 = *(const half8*)(wb + (size_t)m * Nn + jb0 + q * 8);
  half8 B1 = *(const half8*)(wb + (size_t)(16 + m) * Nn + jb0 + q * 8);
  H8 E, F;
  E.h8 = *(const half8*)&Ef[jb0 + q * 8];
  F.h8 = *(const half8*)&Ff[jb0 + q * 8];

#pragma unroll 2
  for (int s = 0; s < 32; ++s) {
    int jn = jb0 + ((s + 1) & 31) * 32;  // wrap: last iter reloads step 0 (unused)
    half8 nB0 = *(const half8*)(wb + (size_t)m * Nn + jn + q * 8);
    half8 nB1 = *(const half8*)(wb + (size_t)(16 + m) * Nn + jn + q * 8);
    H8 nE, nF;
    nE.h8 = *(const half8*)&Ef[jn + q * 8];
    nF.h8 = *(const half8*)&Ff[jn + q * 8];

    H8 P;
#pragma unroll
    for (int kk = 0; kk < 4; ++kk) {
      half2v pe = aa * E.h2[kk];                     // v_pk_mul_f16
      half2v pf = bb * F.h2[kk];                     // v_pk_mul_f16
      P.h2[kk] = __builtin_elementwise_max(pe, pf);  // v_pk_max_f16
    }
    acc0 = __builtin_amdgcn_mfma_f32_16x16x32_f16(P.h8, B0, acc0, 0, 0, 0);
    acc1 = __builtin_amdgcn_mfma_f32_16x16x32_f16(P.h8, B1, acc1, 0, 0, 0);
    accd = __builtin_amdgcn_mfma_f32_16x16x32_f16(P.h8, bden, accd, 0, 0, 0);

    B0 = nB0; B1 = nB1; E = nE; F = nF;
  }

  // ---- epilogue: cross-j-half reduce + divide + elu + store ----
  __syncthreads();  // E/F dead; reuse smem
  float* redN = smem;         // [2 wj][64 rows][33] -> floats 0..4221
  float* redD = smem + 4224;  // [2 wj][64 rows]     -> floats 4224..4351
  {
    int row = wrg * 16 + q * 4;  // 0..63 within tile
#pragma unroll
    for (int dh = 0; dh < 2; ++dh) {
      f32x4 v = dh ? acc1 : acc0;
#pragma unroll
      for (int r = 0; r < 4; ++r)
        redN[(wj * 64 + row + r) * 33 + dh * 16 + m] = v[r];
    }
    if (m == 0) {
#pragma unroll
      for (int r = 0; r < 4; ++r) redD[wj * 64 + row + r] = accd[r];
    }
  }
  __syncthreads();
  {
    int rl = tid >> 3, dg = (tid & 7) * 4;  // 64 rows x 8 groups of 4 d
    float num[4];
#pragma unroll
    for (int i = 0; i < 4; ++i)
      num[i] = redN[rl * 33 + dg + i] + redN[(64 + rl) * 33 + dg + i];
    float dt = redD[rl] + redD[64 + rl];
    float rd = 1.0f / dt;  // den >= ~1 by construction
    float* orow = out + (size_t)(b * Nn + tile * 64 + rl) * (4 * Dd) + h * Dd + dg;
#pragma unroll
    for (int i = 0; i < 4; ++i) {
      float hv = num[i] * rd;
      num[i] = hv > 0.f ? hv : (__builtin_amdgcn_exp2f(hv * LOG2E) - 1.0f);
    }
    *(float4*)orow = make_float4(num[0], num[1], num[2], num[3]);
  }
}

extern "C" void kernel_launch(void* const* d_in, const int* in_sizes, int n_in,
                              void* d_out, int out_size, void* d_ws, size_t ws_size,
                              hipStream_t stream) {
  const float* x = (const float*)d_in[0];   // (4,2048,128)
  const float* W = (const float*)d_in[1];   // (4,128,32)
  const float* a = (const float*)d_in[2];   // (4,64)
  float* out = (float*)d_out;               // (4,2048,128)

  float* wsf = (float*)d_ws;
  float* sArr = wsf;                          // 32768 f32
  float* tArr = sArr + 32768;                 // 32768 f32
  _Float16* whT = (_Float16*)(tArr + 32768);  // 16*32*2048 f16 = 2 MB

  k1_wh<<<dim3(512), dim3(256), 0, stream>>>(x, W, a, whT, sArr, tArr);
  k3_attn<<<dim3(512), dim3(512), 0, stream>>>(whT, sArr, tArr, out);
}

// Round 8
// 76.412 us; speedup vs baseline: 1.2451x; 1.2451x over previous
//
#include <hip/hip_runtime.h>

// GAT dense attention, two kernels (kernel boundary = the inter-phase barrier;
// in-kernel device-scope fences measured catastrophic in round 2: ~85us stall).
// Softmax numerator factorized rank-1:
//   p_ij = exp(max(z, 0.2z)), z = s_i + t_j  ->  max(alpha_i*E_j, beta_i*F_j)
// Shapes: B=4, N=2048, F_in=128, H=4, d=32. out[b][n][h*32+d] fp32.
//
// k1: round-5 hardware-verified, byte-identical.
// k3: round-5 structure (512 blocks x 4 waves, 4-t amortization — round-7
//     proved amortization >> occupancy here), pipeline depth 1 -> 2:
//     ping-pong register buffers, loads for steps s+2/s+3 issued before
//     computing s/s+1, to cover the ~400-600cy Infinity-Cache latency on
//     whT (written by other XCDs; local L2 misses after kernel boundary).

#define LOG2E 1.4426950408889634f
constexpr int Nn = 2048, Fin = 128, Dd = 32;

typedef _Float16 half8 __attribute__((ext_vector_type(8)));
typedef _Float16 half4v __attribute__((ext_vector_type(4)));
typedef _Float16 half2v __attribute__((ext_vector_type(2)));
typedef float f32x4 __attribute__((ext_vector_type(4)));

union H8 { half2v h2[4]; half8 h8; };

// ---------------- Kernel 1: Wh = x @ W (f16 hi/lo 3-MFMA), s, t, whT --------
// 512 blocks (16 bh x 32 tiles of 64 rows) x 256 thr; wave = one 16-row M-tile.
// W pre-split hi/lo into one LDS buffer (coalesced, once per block), replacing
// 64 strided scalar global loads + ~200 cvt VALU per lane in the MFMA loop.
__global__ __launch_bounds__(256) void k1_wh(
    const float* __restrict__ x, const float* __restrict__ W,
    const float* __restrict__ a, _Float16* __restrict__ whT,
    float* __restrict__ sArr, float* __restrict__ tArr) {
  constexpr int KLD = 136;  // halves; mult of 8 -> 16B-aligned b128 reads
  __shared__ __align__(16) _Float16 Wlds[2 * 32 * KLD];  // [hi|lo][d][k]
  _Float16* BhL = Wlds;            // explicit offsets within ONE allocation
  _Float16* BlL = Wlds + 32 * KLD;

  int blk = blockIdx.x;
  int bh = blk >> 5, tile = blk & 31;
  int b = bh >> 2, h = bh & 3;
  int tid = threadIdx.x, w = tid >> 6, lane = tid & 63;
  int q = lane >> 4, m = lane & 15;
  int rowbase = tile * 64 + w * 16;

  const float* Wq = W + h * Fin * Dd;
  {
    // thread: k = tid>>1 (0..127), d = (tid&1)*16 .. +15. Fully coalesced.
    int k = tid >> 1, dbase = (tid & 1) * 16;
    const float* wp = Wq + k * Dd + dbase;
    float4 w0 = *(const float4*)(wp);
    float4 w1 = *(const float4*)(wp + 4);
    float4 w2 = *(const float4*)(wp + 8);
    float4 w3 = *(const float4*)(wp + 12);
    float wv[16] = {w0.x, w0.y, w0.z, w0.w, w1.x, w1.y, w1.z, w1.w,
                    w2.x, w2.y, w2.z, w2.w, w3.x, w3.y, w3.z, w3.w};
#pragma unroll
    for (int u = 0; u < 16; ++u) {
      _Float16 hi = (_Float16)wv[u];
      BhL[(dbase + u) * KLD + k] = hi;
      BlL[(dbase + u) * KLD + k] = (_Float16)(wv[u] - (float)hi);
    }
  }
  __syncthreads();

  const float* xb = x + (size_t)(b * Nn + rowbase + m) * Fin;
  f32x4 acc[2];
  acc[0] = (f32x4){0.f, 0.f, 0.f, 0.f};
  acc[1] = (f32x4){0.f, 0.f, 0.f, 0.f};

#pragma unroll
  for (int kt = 0; kt < 4; ++kt) {
    float4 x0 = *(const float4*)(xb + kt * 32 + q * 8);
    float4 x1 = *(const float4*)(xb + kt * 32 + q * 8 + 4);
    float xv[8] = {x0.x, x0.y, x0.z, x0.w, x1.x, x1.y, x1.z, x1.w};
    half8 Ah, Al;
#pragma unroll
    for (int j = 0; j < 8; ++j) {
      _Float16 hi = (_Float16)xv[j];
      Ah[j] = hi;
      Al[j] = (_Float16)(xv[j] - (float)hi);
    }
#pragma unroll
    for (int nt = 0; nt < 2; ++nt) {
      int off = (nt * 16 + m) * KLD + kt * 32 + q * 8;
      half8 Bh = *(const half8*)&BhL[off];
      half8 Bl = *(const half8*)&BlL[off];
      acc[nt] = __builtin_amdgcn_mfma_f32_16x16x32_f16(Ah, Bh, acc[nt], 0, 0, 0);
      acc[nt] = __builtin_amdgcn_mfma_f32_16x16x32_f16(Al, Bh, acc[nt], 0, 0, 0);
      acc[nt] = __builtin_amdgcn_mfma_f32_16x16x32_f16(Ah, Bl, acc[nt], 0, 0, 0);
    }
  }

  // C layout: lane(q,m) -> rows rowbase+q*4+r, col d = nt*16+m.
#pragma unroll
  for (int nt = 0; nt < 2; ++nt) {
    int d = nt * 16 + m;
    half4v h4;
#pragma unroll
    for (int r = 0; r < 4; ++r) h4[r] = (_Float16)acc[nt][r];
    *(half4v*)(whT + (size_t)(bh * Dd + d) * Nn + rowbase + q * 4) = h4;
  }

  const float* ah = a + h * 2 * Dd;
  float a1m0 = ah[m], a1m1 = ah[16 + m];
  float a2m0 = ah[Dd + m], a2m1 = ah[Dd + 16 + m];
#pragma unroll
  for (int r = 0; r < 4; ++r) {
    float ps = acc[0][r] * a1m0 + acc[1][r] * a1m1;
    float pt = acc[0][r] * a2m0 + acc[1][r] * a2m1;
#pragma unroll
    for (int off = 1; off < 16; off <<= 1) {
      ps += __shfl_xor(ps, off);
      pt += __shfl_xor(pt, off);
    }
    if (m == 0) {
      sArr[bh * Nn + rowbase + q * 4 + r] = ps;
      tArr[bh * Nn + rowbase + q * 4 + r] = pt;
    }
  }
}

// ---------------- Kernel 3: h = softmax(e) @ Wh via f16 MFMA ----------------
// 512 blocks (16 bh x 32 tiles of 64 rows) x 256 thr = 4 waves (j-quarters).
// Verified round-5 structure; main loop pipelined to depth 2 (ping-pong regs).
__global__ __launch_bounds__(256) void k3_attn(
    const _Float16* __restrict__ whT, const float* __restrict__ sArr,
    const float* __restrict__ tArr, float* __restrict__ out) {
  __shared__ float smem[4 * 64 * 33 + 256];  // 34.8 KB union
  _Float16* Ef = (_Float16*)smem;            // [2048] f16 (1024 f32 slots)
  _Float16* Ff = (_Float16*)(smem + 1024);   // [2048] f16
  float* red = smem + 2048;                  // [256] block-max scratch

  int blk = blockIdx.x;
  int bh = blk >> 5, tile = blk & 31;
  int b = bh >> 2, h = bh & 3;
  int tid = threadIdx.x, w = tid >> 6, lane = tid & 63;
  int q = lane >> 4, m = lane & 15;

  // ---- prologue: T, then E_j = 2^(L(t-T)), F_j = 2^(0.2L(t-T)) ----
  float tv[8];
  float mx = -1e30f;
#pragma unroll
  for (int k = 0; k < 8; ++k) {
    tv[k] = tArr[bh * Nn + tid + k * 256];
    mx = fmaxf(mx, tv[k]);
  }
  red[tid] = mx;
  __syncthreads();
  for (int ss = 128; ss > 0; ss >>= 1) {
    if (tid < ss) red[tid] = fmaxf(red[tid], red[tid + ss]);
    __syncthreads();
  }
  float T = red[0];
  __syncthreads();  // red region dead before Ef overwrite (disjoint anyway)
#pragma unroll
  for (int k = 0; k < 8; ++k) {
    float dt = tv[k] - T;  // <= 0
    Ef[tid + k * 256] = (_Float16)__builtin_amdgcn_exp2f(LOG2E * dt);
    Ff[tid + k * 256] = (_Float16)__builtin_amdgcn_exp2f(0.2f * LOG2E * dt);
  }

  // per-row alpha/beta (replicated f16 pairs)
  half2v aa[4], bb[4];
#pragma unroll
  for (int t = 0; t < 4; ++t) {
    float es = sArr[bh * Nn + tile * 64 + t * 16 + m] + T;
    float al = __builtin_amdgcn_exp2f(0.8f * LOG2E * fminf(es, 0.f));
    float be = __builtin_amdgcn_exp2f(-0.8f * LOG2E * fmaxf(es, 0.f));
    _Float16 ah_ = (_Float16)al, bh_ = (_Float16)be;
    aa[t] = (half2v){ah_, ah_};
    bb[t] = (half2v){bh_, bh_};
  }
  __syncthreads();  // E/F visible to all waves

  f32x4 acc[4][2];
  f32x4 accd[4];
#pragma unroll
  for (int t = 0; t < 4; ++t) {
    acc[t][0] = (f32x4){0.f, 0.f, 0.f, 0.f};
    acc[t][1] = (f32x4){0.f, 0.f, 0.f, 0.f};
    accd[t] = (f32x4){0.f, 0.f, 0.f, 0.f};
  }
  // den via MFMA: B fragment = ones in column 0 (lanes m==0), zero elsewhere.
  half8 bden;
  {
    _Float16 v = (_Float16)((m == 0) ? 1.f : 0.f);
#pragma unroll
    for (int j = 0; j < 8; ++j) bden[j] = v;
  }

  const _Float16* wb = whT + (size_t)bh * Dd * Nn;
  const int jb0 = w * 512;
  const _Float16* wb0 = wb + (size_t)m * Nn + jb0;
  const _Float16* wb1 = wb + (size_t)(16 + m) * Nn + jb0;

  // ---- main loop: 16 steps of 32 j, depth-2 pipeline, no barriers/exp ----
  half8 B0a = *(const half8*)(wb0 + q * 8);
  half8 B1a = *(const half8*)(wb1 + q * 8);
  H8 Ea, Fa, Eb, Fb;
  Ea.h8 = *(const half8*)&Ef[jb0 + q * 8];
  Fa.h8 = *(const half8*)&Ff[jb0 + q * 8];
  half8 B0b = *(const half8*)(wb0 + 32 + q * 8);
  half8 B1b = *(const half8*)(wb1 + 32 + q * 8);
  Eb.h8 = *(const half8*)&Ef[jb0 + 32 + q * 8];
  Fb.h8 = *(const half8*)&Ff[jb0 + 32 + q * 8];

  for (int s = 0; s < 16; s += 2) {
    int j2 = ((s + 2) & 15) * 32;  // wrap: final iter's loads unused
    int j3 = ((s + 3) & 15) * 32;
    half8 nB0a = *(const half8*)(wb0 + j2 + q * 8);
    half8 nB1a = *(const half8*)(wb1 + j2 + q * 8);
    H8 nEa, nFa, nEb, nFb;
    nEa.h8 = *(const half8*)&Ef[jb0 + j2 + q * 8];
    nFa.h8 = *(const half8*)&Ff[jb0 + j2 + q * 8];
    half8 nB0b = *(const half8*)(wb0 + j3 + q * 8);
    half8 nB1b = *(const half8*)(wb1 + j3 + q * 8);
    nEb.h8 = *(const half8*)&Ef[jb0 + j3 + q * 8];
    nFb.h8 = *(const half8*)&Ff[jb0 + j3 + q * 8];

    // step s (buffers a)
#pragma unroll
    for (int t = 0; t < 4; ++t) {
      H8 P;
#pragma unroll
      for (int kk = 0; kk < 4; ++kk) {
        half2v pe = aa[t] * Ea.h2[kk];                 // v_pk_mul_f16
        half2v pf = bb[t] * Fa.h2[kk];                 // v_pk_mul_f16
        P.h2[kk] = __builtin_elementwise_max(pe, pf);  // v_pk_max_f16
      }
      acc[t][0] = __builtin_amdgcn_mfma_f32_16x16x32_f16(P.h8, B0a, acc[t][0], 0, 0, 0);
      acc[t][1] = __builtin_amdgcn_mfma_f32_16x16x32_f16(P.h8, B1a, acc[t][1], 0, 0, 0);
      accd[t]  = __builtin_amdgcn_mfma_f32_16x16x32_f16(P.h8, bden, accd[t], 0, 0, 0);
    }
    // step s+1 (buffers b)
#pragma unroll
    for (int t = 0; t < 4; ++t) {
      H8 P;
#pragma unroll
      for (int kk = 0; kk < 4; ++kk) {
        half2v pe = aa[t] * Eb.h2[kk];
        half2v pf = bb[t] * Fb.h2[kk];
        P.h2[kk] = __builtin_elementwise_max(pe, pf);
      }
      acc[t][0] = __builtin_amdgcn_mfma_f32_16x16x32_f16(P.h8, B0b, acc[t][0], 0, 0, 0);
      acc[t][1] = __builtin_amdgcn_mfma_f32_16x16x32_f16(P.h8, B1b, acc[t][1], 0, 0, 0);
      accd[t]  = __builtin_amdgcn_mfma_f32_16x16x32_f16(P.h8, bden, accd[t], 0, 0, 0);
    }
    B0a = nB0a; B1a = nB1a; Ea = nEa; Fa = nFa;
    B0b = nB0b; B1b = nB1b; Eb = nEb; Fb = nFb;
  }

  // ---- epilogue: cross-wave reduce + divide + elu + store ----
  __syncthreads();  // E/F dead; reuse smem
  float* redN = smem;                // [4][64][33]
  float* redD = smem + 4 * 64 * 33;  // [4][64]
#pragma unroll
  for (int t = 0; t < 4; ++t) {
#pragma unroll
    for (int dh = 0; dh < 2; ++dh)
#pragma unroll
      for (int r = 0; r < 4; ++r)
        redN[(w * 64 + t * 16 + q * 4 + r) * 33 + dh * 16 + m] = acc[t][dh][r];
    if (m == 0) {
#pragma unroll
      for (int r = 0; r < 4; ++r)
        redD[w * 64 + t * 16 + q * 4 + r] = accd[t][r];  // den at col-0 lanes
    }
  }
  __syncthreads();
  {
    int rl = tid >> 2, dg = (tid & 3) * 8;
    float num[8];
#pragma unroll
    for (int i = 0; i < 8; ++i)
      num[i] = redN[(0 * 64 + rl) * 33 + dg + i] + redN[(1 * 64 + rl) * 33 + dg + i] +
               redN[(2 * 64 + rl) * 33 + dg + i] + redN[(3 * 64 + rl) * 33 + dg + i];
    float dt = redD[rl] + redD[64 + rl] + redD[128 + rl] + redD[192 + rl];
    float rd = 1.0f / dt;  // den >= ~1 by construction
    float* orow = out + (size_t)(b * Nn + tile * 64 + rl) * (4 * Dd) + h * Dd + dg;
#pragma unroll
    for (int i = 0; i < 8; ++i) {
      float hv = num[i] * rd;
      num[i] = hv > 0.f ? hv : (__builtin_amdgcn_exp2f(hv * LOG2E) - 1.0f);
    }
    *(float4*)orow = make_float4(num[0], num[1], num[2], num[3]);
    *((float4*)orow + 1) = make_float4(num[4], num[5], num[6], num[7]);
  }
}

extern "C" void kernel_launch(void* const* d_in, const int* in_sizes, int n_in,
                              void* d_out, int out_size, void* d_ws, size_t ws_size,
                              hipStream_t stream) {
  const float* x = (const float*)d_in[0];   // (4,2048,128)
  const float* W = (const float*)d_in[1];   // (4,128,32)
  const float* a = (const float*)d_in[2];   // (4,64)
  float* out = (float*)d_out;               // (4,2048,128)

  float* wsf = (float*)d_ws;
  float* sArr = wsf;                          // 32768 f32
  float* tArr = sArr + 32768;                 // 32768 f32
  _Float16* whT = (_Float16*)(tArr + 32768);  // 16*32*2048 f16 = 2 MB

  k1_wh<<<dim3(512), dim3(256), 0, stream>>>(x, W, a, whT, sArr, tArr);
  k3_attn<<<dim3(512), dim3(256), 0, stream>>>(whT, sArr, tArr, out);
}

// Round 9
// 74.512 us; speedup vs baseline: 1.2769x; 1.0255x over previous
//
#include <hip/hip_runtime.h>

// GAT dense attention, two kernels (kernel boundary = the inter-phase barrier;
// in-kernel device-scope fences measured catastrophic in round 2: ~85us stall).
// Softmax numerator factorized rank-1:
//   p_ij = exp(max(z, 0.2z)), z = s_i + t_j  ->  max(alpha_i*E_j, beta_i*F_j)
// Shapes: B=4, N=2048, F_in=128, H=4, d=32. out[b][n][h*32+d] fp32.
//
// This round's single change: XCD-aligned block mapping. bh = blk&15 (not
// blk>>5) puts all 32 producer (k1) and all 32 consumer (k3) blocks of a
// given bh on the SAME XCD (XCD = blk%8 round-robin), so whT[bh] (128KB)
// is written and read within one XCD's 4MB L2 instead of crossing to L3.
// Pure index bijection — zero arithmetic change vs the round-8-verified
// kernel (76.41us, absmax 0.015625).

#define LOG2E 1.4426950408889634f
constexpr int Nn = 2048, Fin = 128, Dd = 32;

typedef _Float16 half8 __attribute__((ext_vector_type(8)));
typedef _Float16 half4v __attribute__((ext_vector_type(4)));
typedef _Float16 half2v __attribute__((ext_vector_type(2)));
typedef float f32x4 __attribute__((ext_vector_type(4)));

union H8 { half2v h2[4]; half8 h8; };

// ---------------- Kernel 1: Wh = x @ W (f16 hi/lo 3-MFMA), s, t, whT --------
// 512 blocks (16 bh x 32 tiles of 64 rows) x 256 thr; wave = one 16-row M-tile.
// W pre-split hi/lo into one LDS buffer (coalesced, once per block), replacing
// 64 strided scalar global loads + ~200 cvt VALU per lane in the MFMA loop.
__global__ __launch_bounds__(256) void k1_wh(
    const float* __restrict__ x, const float* __restrict__ W,
    const float* __restrict__ a, _Float16* __restrict__ whT,
    float* __restrict__ sArr, float* __restrict__ tArr) {
  constexpr int KLD = 136;  // halves; mult of 8 -> 16B-aligned b128 reads
  __shared__ __align__(16) _Float16 Wlds[2 * 32 * KLD];  // [hi|lo][d][k]
  _Float16* BhL = Wlds;            // explicit offsets within ONE allocation
  _Float16* BlL = Wlds + 32 * KLD;

  int blk = blockIdx.x;
  int bh = blk & 15, tile = blk >> 4;  // XCD-aligned: same-bh blocks on XCD bh%8
  int b = bh >> 2, h = bh & 3;
  int tid = threadIdx.x, w = tid >> 6, lane = tid & 63;
  int q = lane >> 4, m = lane & 15;
  int rowbase = tile * 64 + w * 16;

  const float* Wq = W + h * Fin * Dd;
  {
    // thread: k = tid>>1 (0..127), d = (tid&1)*16 .. +15. Fully coalesced.
    int k = tid >> 1, dbase = (tid & 1) * 16;
    const float* wp = Wq + k * Dd + dbase;
    float4 w0 = *(const float4*)(wp);
    float4 w1 = *(const float4*)(wp + 4);
    float4 w2 = *(const float4*)(wp + 8);
    float4 w3 = *(const float4*)(wp + 12);
    float wv[16] = {w0.x, w0.y, w0.z, w0.w, w1.x, w1.y, w1.z, w1.w,
                    w2.x, w2.y, w2.z, w2.w, w3.x, w3.y, w3.z, w3.w};
#pragma unroll
    for (int u = 0; u < 16; ++u) {
      _Float16 hi = (_Float16)wv[u];
      BhL[(dbase + u) * KLD + k] = hi;
      BlL[(dbase + u) * KLD + k] = (_Float16)(wv[u] - (float)hi);
    }
  }
  __syncthreads();

  const float* xb = x + (size_t)(b * Nn + rowbase + m) * Fin;
  f32x4 acc[2];
  acc[0] = (f32x4){0.f, 0.f, 0.f, 0.f};
  acc[1] = (f32x4){0.f, 0.f, 0.f, 0.f};

#pragma unroll
  for (int kt = 0; kt < 4; ++kt) {
    float4 x0 = *(const float4*)(xb + kt * 32 + q * 8);
    float4 x1 = *(const float4*)(xb + kt * 32 + q * 8 + 4);
    float xv[8] = {x0.x, x0.y, x0.z, x0.w, x1.x, x1.y, x1.z, x1.w};
    half8 Ah, Al;
#pragma unroll
    for (int j = 0; j < 8; ++j) {
      _Float16 hi = (_Float16)xv[j];
      Ah[j] = hi;
      Al[j] = (_Float16)(xv[j] - (float)hi);
    }
#pragma unroll
    for (int nt = 0; nt < 2; ++nt) {
      int off = (nt * 16 + m) * KLD + kt * 32 + q * 8;
      half8 Bh = *(const half8*)&BhL[off];
      half8 Bl = *(const half8*)&BlL[off];
      acc[nt] = __builtin_amdgcn_mfma_f32_16x16x32_f16(Ah, Bh, acc[nt], 0, 0, 0);
      acc[nt] = __builtin_amdgcn_mfma_f32_16x16x32_f16(Al, Bh, acc[nt], 0, 0, 0);
      acc[nt] = __builtin_amdgcn_mfma_f32_16x16x32_f16(Ah, Bl, acc[nt], 0, 0, 0);
    }
  }

  // C layout: lane(q,m) -> rows rowbase+q*4+r, col d = nt*16+m.
#pragma unroll
  for (int nt = 0; nt < 2; ++nt) {
    int d = nt * 16 + m;
    half4v h4;
#pragma unroll
    for (int r = 0; r < 4; ++r) h4[r] = (_Float16)acc[nt][r];
    *(half4v*)(whT + (size_t)(bh * Dd + d) * Nn + rowbase + q * 4) = h4;
  }

  const float* ah = a + h * 2 * Dd;
  float a1m0 = ah[m], a1m1 = ah[16 + m];
  float a2m0 = ah[Dd + m], a2m1 = ah[Dd + 16 + m];
#pragma unroll
  for (int r = 0; r < 4; ++r) {
    float ps = acc[0][r] * a1m0 + acc[1][r] * a1m1;
    float pt = acc[0][r] * a2m0 + acc[1][r] * a2m1;
#pragma unroll
    for (int off = 1; off < 16; off <<= 1) {
      ps += __shfl_xor(ps, off);
      pt += __shfl_xor(pt, off);
    }
    if (m == 0) {
      sArr[bh * Nn + rowbase + q * 4 + r] = ps;
      tArr[bh * Nn + rowbase + q * 4 + r] = pt;
    }
  }
}

// ---------------- Kernel 3: h = softmax(e) @ Wh via f16 MFMA ----------------
// 512 blocks (16 bh x 32 tiles of 64 rows) x 256 thr = 4 waves (j-quarters).
// Verified round-8 structure (depth-2 ping-pong pipeline, MFMA-den).
__global__ __launch_bounds__(256) void k3_attn(
    const _Float16* __restrict__ whT, const float* __restrict__ sArr,
    const float* __restrict__ tArr, float* __restrict__ out) {
  __shared__ float smem[4 * 64 * 33 + 256];  // 34.8 KB union
  _Float16* Ef = (_Float16*)smem;            // [2048] f16 (1024 f32 slots)
  _Float16* Ff = (_Float16*)(smem + 1024);   // [2048] f16
  float* red = smem + 2048;                  // [256] block-max scratch

  int blk = blockIdx.x;
  int bh = blk & 15, tile = blk >> 4;  // XCD-aligned: matches k1's mapping
  int b = bh >> 2, h = bh & 3;
  int tid = threadIdx.x, w = tid >> 6, lane = tid & 63;
  int q = lane >> 4, m = lane & 15;

  // ---- prologue: T, then E_j = 2^(L(t-T)), F_j = 2^(0.2L(t-T)) ----
  float tv[8];
  float mx = -1e30f;
#pragma unroll
  for (int k = 0; k < 8; ++k) {
    tv[k] = tArr[bh * Nn + tid + k * 256];
    mx = fmaxf(mx, tv[k]);
  }
  red[tid] = mx;
  __syncthreads();
  for (int ss = 128; ss > 0; ss >>= 1) {
    if (tid < ss) red[tid] = fmaxf(red[tid], red[tid + ss]);
    __syncthreads();
  }
  float T = red[0];
  __syncthreads();  // red region dead before Ef overwrite (disjoint anyway)
#pragma unroll
  for (int k = 0; k < 8; ++k) {
    float dt = tv[k] - T;  // <= 0
    Ef[tid + k * 256] = (_Float16)__builtin_amdgcn_exp2f(LOG2E * dt);
    Ff[tid + k * 256] = (_Float16)__builtin_amdgcn_exp2f(0.2f * LOG2E * dt);
  }

  // per-row alpha/beta (replicated f16 pairs)
  half2v aa[4], bb[4];
#pragma unroll
  for (int t = 0; t < 4; ++t) {
    float es = sArr[bh * Nn + tile * 64 + t * 16 + m] + T;
    float al = __builtin_amdgcn_exp2f(0.8f * LOG2E * fminf(es, 0.f));
    float be = __builtin_amdgcn_exp2f(-0.8f * LOG2E * fmaxf(es, 0.f));
    _Float16 ah_ = (_Float16)al, bh_ = (_Float16)be;
    aa[t] = (half2v){ah_, ah_};
    bb[t] = (half2v){bh_, bh_};
  }
  __syncthreads();  // E/F visible to all waves

  f32x4 acc[4][2];
  f32x4 accd[4];
#pragma unroll
  for (int t = 0; t < 4; ++t) {
    acc[t][0] = (f32x4){0.f, 0.f, 0.f, 0.f};
    acc[t][1] = (f32x4){0.f, 0.f, 0.f, 0.f};
    accd[t] = (f32x4){0.f, 0.f, 0.f, 0.f};
  }
  // den via MFMA: B fragment = ones in column 0 (lanes m==0), zero elsewhere.
  half8 bden;
  {
    _Float16 v = (_Float16)((m == 0) ? 1.f : 0.f);
#pragma unroll
    for (int j = 0; j < 8; ++j) bden[j] = v;
  }

  const _Float16* wb = whT + (size_t)bh * Dd * Nn;
  const int jb0 = w * 512;
  const _Float16* wb0 = wb + (size_t)m * Nn + jb0;
  const _Float16* wb1 = wb + (size_t)(16 + m) * Nn + jb0;

  // ---- main loop: 16 steps of 32 j, depth-2 pipeline, no barriers/exp ----
  half8 B0a = *(const half8*)(wb0 + q * 8);
  half8 B1a = *(const half8*)(wb1 + q * 8);
  H8 Ea, Fa, Eb, Fb;
  Ea.h8 = *(const half8*)&Ef[jb0 + q * 8];
  Fa.h8 = *(const half8*)&Ff[jb0 + q * 8];
  half8 B0b = *(const half8*)(wb0 + 32 + q * 8);
  half8 B1b = *(const half8*)(wb1 + 32 + q * 8);
  Eb.h8 = *(const half8*)&Ef[jb0 + 32 + q * 8];
  Fb.h8 = *(const half8*)&Ff[jb0 + 32 + q * 8];

  for (int s = 0; s < 16; s += 2) {
    int j2 = ((s + 2) & 15) * 32;  // wrap: final iter's loads unused
    int j3 = ((s + 3) & 15) * 32;
    half8 nB0a = *(const half8*)(wb0 + j2 + q * 8);
    half8 nB1a = *(const half8*)(wb1 + j2 + q * 8);
    H8 nEa, nFa, nEb, nFb;
    nEa.h8 = *(const half8*)&Ef[jb0 + j2 + q * 8];
    nFa.h8 = *(const half8*)&Ff[jb0 + j2 + q * 8];
    half8 nB0b = *(const half8*)(wb0 + j3 + q * 8);
    half8 nB1b = *(const half8*)(wb1 + j3 + q * 8);
    nEb.h8 = *(const half8*)&Ef[jb0 + j3 + q * 8];
    nFb.h8 = *(const half8*)&Ff[jb0 + j3 + q * 8];

    // step s (buffers a)
#pragma unroll
    for (int t = 0; t < 4; ++t) {
      H8 P;
#pragma unroll
      for (int kk = 0; kk < 4; ++kk) {
        half2v pe = aa[t] * Ea.h2[kk];                 // v_pk_mul_f16
        half2v pf = bb[t] * Fa.h2[kk];                 // v_pk_mul_f16
        P.h2[kk] = __builtin_elementwise_max(pe, pf);  // v_pk_max_f16
      }
      acc[t][0] = __builtin_amdgcn_mfma_f32_16x16x32_f16(P.h8, B0a, acc[t][0], 0, 0, 0);
      acc[t][1] = __builtin_amdgcn_mfma_f32_16x16x32_f16(P.h8, B1a, acc[t][1], 0, 0, 0);
      accd[t]  = __builtin_amdgcn_mfma_f32_16x16x32_f16(P.h8, bden, accd[t], 0, 0, 0);
    }
    // step s+1 (buffers b)
#pragma unroll
    for (int t = 0; t < 4; ++t) {
      H8 P;
#pragma unroll
      for (int kk = 0; kk < 4; ++kk) {
        half2v pe = aa[t] * Eb.h2[kk];
        half2v pf = bb[t] * Fb.h2[kk];
        P.h2[kk] = __builtin_elementwise_max(pe, pf);
      }
      acc[t][0] = __builtin_amdgcn_mfma_f32_16x16x32_f16(P.h8, B0b, acc[t][0], 0, 0, 0);
      acc[t][1] = __builtin_amdgcn_mfma_f32_16x16x32_f16(P.h8, B1b, acc[t][1], 0, 0, 0);
      accd[t]  = __builtin_amdgcn_mfma_f32_16x16x32_f16(P.h8, bden, accd[t], 0, 0, 0);
    }
    B0a = nB0a; B1a = nB1a; Ea = nEa; Fa = nFa;
    B0b = nB0b; B1b = nB1b; Eb = nEb; Fb = nFb;
  }

  // ---- epilogue: cross-wave reduce + divide + elu + store ----
  __syncthreads();  // E/F dead; reuse smem
  float* redN = smem;                // [4][64][33]
  float* redD = smem + 4 * 64 * 33;  // [4][64]
#pragma unroll
  for (int t = 0; t < 4; ++t) {
#pragma unroll
    for (int dh = 0; dh < 2; ++dh)
#pragma unroll
      for (int r = 0; r < 4; ++r)
        redN[(w * 64 + t * 16 + q * 4 + r) * 33 + dh * 16 + m] = acc[t][dh][r];
    if (m == 0) {
#pragma unroll
      for (int r = 0; r < 4; ++r)
        redD[w * 64 + t * 16 + q * 4 + r] = accd[t][r];  // den at col-0 lanes
    }
  }
  __syncthreads();
  {
    int rl = tid >> 2, dg = (tid & 3) * 8;
    float num[8];
#pragma unroll
    for (int i = 0; i < 8; ++i)
      num[i] = redN[(0 * 64 + rl) * 33 + dg + i] + redN[(1 * 64 + rl) * 33 + dg + i] +
               redN[(2 * 64 + rl) * 33 + dg + i] + redN[(3 * 64 + rl) * 33 + dg + i];
    float dt = redD[rl] + redD[64 + rl] + redD[128 + rl] + redD[192 + rl];
    float rd = 1.0f / dt;  // den >= ~1 by construction
    float* orow = out + (size_t)(b * Nn + tile * 64 + rl) * (4 * Dd) + h * Dd + dg;
#pragma unroll
    for (int i = 0; i < 8; ++i) {
      float hv = num[i] * rd;
      num[i] = hv > 0.f ? hv : (__builtin_amdgcn_exp2f(hv * LOG2E) - 1.0f);
    }
    *(float4*)orow = make_float4(num[0], num[1], num[2], num[3]);
    *((float4*)orow + 1) = make_float4(num[4], num[5], num[6], num[7]);
  }
}

extern "C" void kernel_launch(void* const* d_in, const int* in_sizes, int n_in,
                              void* d_out, int out_size, void* d_ws, size_t ws_size,
                              hipStream_t stream) {
  const float* x = (const float*)d_in[0];   // (4,2048,128)
  const float* W = (const float*)d_in[1];   // (4,128,32)
  const float* a = (const float*)d_in[2];   // (4,64)
  float* out = (float*)d_out;               // (4,2048,128)

  float* wsf = (float*)d_ws;
  float* sArr = wsf;                          // 32768 f32
  float* tArr = sArr + 32768;                 // 32768 f32
  _Float16* whT = (_Float16*)(tArr + 32768);  // 16*32*2048 f16 = 2 MB

  k1_wh<<<dim3(512), dim3(256), 0, stream>>>(x, W, a, whT, sArr, tArr);
  k3_attn<<<dim3(512), dim3(256), 0, stream>>>(whT, sArr, tArr, out);
}

// Round 11
// 74.464 us; speedup vs baseline: 1.2777x; 1.0006x over previous
//
#include <hip/hip_runtime.h>

// GAT dense attention, two kernels (kernel boundary = the inter-phase barrier;
// in-kernel device-scope fences measured catastrophic in round 2: ~85us stall).
// Softmax numerator factorized rank-1:
//   p_ij = exp(max(z, 0.2z)), z = s_i + t_j  ->  max(alpha_i*E_j, beta_i*F_j)
// Shapes: B=4, N=2048, F_in=128, H=4, d=32. out[b][n][h*32+d] fp32.
//
// Round-9 verified: XCD-aligned mapping (bh = blk&15) keeps whT[bh] in one
// XCD's L2 across the kernel boundary (-1.9us). This round (resubmitted
// unchanged after a round-10 infra flake, same signature as round 4's):
// (a) b/h packing swapped to b=bh&3, h=bh>>2 so both bh's on an XCD share
// the SAME x[b] (halves k1's x HBM fetch 16MB->8MB post-fill);
// (b) k3 block-max via wave shuffle + 1 barrier (round-7-verified pattern).
// Both are bijective/index-only changes; arithmetic identical.

#define LOG2E 1.4426950408889634f
constexpr int Nn = 2048, Fin = 128, Dd = 32;

typedef _Float16 half8 __attribute__((ext_vector_type(8)));
typedef _Float16 half4v __attribute__((ext_vector_type(4)));
typedef _Float16 half2v __attribute__((ext_vector_type(2)));
typedef float f32x4 __attribute__((ext_vector_type(4)));

union H8 { half2v h2[4]; half8 h8; };

// ---------------- Kernel 1: Wh = x @ W (f16 hi/lo 3-MFMA), s, t, whT --------
// 512 blocks (16 bh x 32 tiles of 64 rows) x 256 thr; wave = one 16-row M-tile.
// W pre-split hi/lo into one LDS buffer (coalesced, once per block), replacing
// 64 strided scalar global loads + ~200 cvt VALU per lane in the MFMA loop.
__global__ __launch_bounds__(256) void k1_wh(
    const float* __restrict__ x, const float* __restrict__ W,
    const float* __restrict__ a, _Float16* __restrict__ whT,
    float* __restrict__ sArr, float* __restrict__ tArr) {
  constexpr int KLD = 136;  // halves; mult of 8 -> 16B-aligned b128 reads
  __shared__ __align__(16) _Float16 Wlds[2 * 32 * KLD];  // [hi|lo][d][k]
  _Float16* BhL = Wlds;            // explicit offsets within ONE allocation
  _Float16* BlL = Wlds + 32 * KLD;

  int blk = blockIdx.x;
  int bh = blk & 15, tile = blk >> 4;  // XCD-aligned: same-bh blocks on XCD bh%8
  int b = bh & 3, h = bh >> 2;  // b=bh&3: XCD n hosts bh {n,n+8} -> SAME x[b]
  int tid = threadIdx.x, w = tid >> 6, lane = tid & 63;
  int q = lane >> 4, m = lane & 15;
  int rowbase = tile * 64 + w * 16;

  const float* Wq = W + h * Fin * Dd;
  {
    // thread: k = tid>>1 (0..127), d = (tid&1)*16 .. +15. Fully coalesced.
    int k = tid >> 1, dbase = (tid & 1) * 16;
    const float* wp = Wq + k * Dd + dbase;
    float4 w0 = *(const float4*)(wp);
    float4 w1 = *(const float4*)(wp + 4);
    float4 w2 = *(const float4*)(wp + 8);
    float4 w3 = *(const float4*)(wp + 12);
    float wv[16] = {w0.x, w0.y, w0.z, w0.w, w1.x, w1.y, w1.z, w1.w,
                    w2.x, w2.y, w2.z, w2.w, w3.x, w3.y, w3.z, w3.w};
#pragma unroll
    for (int u = 0; u < 16; ++u) {
      _Float16 hi = (_Float16)wv[u];
      BhL[(dbase + u) * KLD + k] = hi;
      BlL[(dbase + u) * KLD + k] = (_Float16)(wv[u] - (float)hi);
    }
  }
  __syncthreads();

  const float* xb = x + (size_t)(b * Nn + rowbase + m) * Fin;
  f32x4 acc[2];
  acc[0] = (f32x4){0.f, 0.f, 0.f, 0.f};
  acc[1] = (f32x4){0.f, 0.f, 0.f, 0.f};

#pragma unroll
  for (int kt = 0; kt < 4; ++kt) {
    float4 x0 = *(const float4*)(xb + kt * 32 + q * 8);
    float4 x1 = *(const float4*)(xb + kt * 32 + q * 8 + 4);
    float xv[8] = {x0.x, x0.y, x0.z, x0.w, x1.x, x1.y, x1.z, x1.w};
    half8 Ah, Al;
#pragma unroll
    for (int j = 0; j < 8; ++j) {
      _Float16 hi = (_Float16)xv[j];
      Ah[j] = hi;
      Al[j] = (_Float16)(xv[j] - (float)hi);
    }
#pragma unroll
    for (int nt = 0; nt < 2; ++nt) {
      int off = (nt * 16 + m) * KLD + kt * 32 + q * 8;
      half8 Bh = *(const half8*)&BhL[off];
      half8 Bl = *(const half8*)&BlL[off];
      acc[nt] = __builtin_amdgcn_mfma_f32_16x16x32_f16(Ah, Bh, acc[nt], 0, 0, 0);
      acc[nt] = __builtin_amdgcn_mfma_f32_16x16x32_f16(Al, Bh, acc[nt], 0, 0, 0);
      acc[nt] = __builtin_amdgcn_mfma_f32_16x16x32_f16(Ah, Bl, acc[nt], 0, 0, 0);
    }
  }

  // C layout: lane(q,m) -> rows rowbase+q*4+r, col d = nt*16+m.
#pragma unroll
  for (int nt = 0; nt < 2; ++nt) {
    int d = nt * 16 + m;
    half4v h4;
#pragma unroll
    for (int r = 0; r < 4; ++r) h4[r] = (_Float16)acc[nt][r];
    *(half4v*)(whT + (size_t)(bh * Dd + d) * Nn + rowbase + q * 4) = h4;
  }

  const float* ah = a + h * 2 * Dd;
  float a1m0 = ah[m], a1m1 = ah[16 + m];
  float a2m0 = ah[Dd + m], a2m1 = ah[Dd + 16 + m];
#pragma unroll
  for (int r = 0; r < 4; ++r) {
    float ps = acc[0][r] * a1m0 + acc[1][r] * a1m1;
    float pt = acc[0][r] * a2m0 + acc[1][r] * a2m1;
#pragma unroll
    for (int off = 1; off < 16; off <<= 1) {
      ps += __shfl_xor(ps, off);
      pt += __shfl_xor(pt, off);
    }
    if (m == 0) {
      sArr[bh * Nn + rowbase + q * 4 + r] = ps;
      tArr[bh * Nn + rowbase + q * 4 + r] = pt;
    }
  }
}

// ---------------- Kernel 3: h = softmax(e) @ Wh via f16 MFMA ----------------
// 512 blocks (16 bh x 32 tiles of 64 rows) x 256 thr = 4 waves (j-quarters).
// Round-9-verified structure (depth-2 ping-pong pipeline, MFMA-den);
// block-max now wave-shuffle + 1 barrier (round-7-verified pattern).
__global__ __launch_bounds__(256) void k3_attn(
    const _Float16* __restrict__ whT, const float* __restrict__ sArr,
    const float* __restrict__ tArr, float* __restrict__ out) {
  __shared__ float smem[4 * 64 * 33 + 256];  // 34.8 KB union
  _Float16* Ef = (_Float16*)smem;            // [2048] f16 (1024 f32 slots)
  _Float16* Ff = (_Float16*)(smem + 1024);   // [2048] f16
  float* red = smem + 2048;                  // [4] wave-max scratch

  int blk = blockIdx.x;
  int bh = blk & 15, tile = blk >> 4;  // XCD-aligned: matches k1's mapping
  int b = bh & 3, h = bh >> 2;         // matches k1's packing
  int tid = threadIdx.x, w = tid >> 6, lane = tid & 63;
  int q = lane >> 4, m = lane & 15;

  // ---- prologue: T via wave-shuffle + 1 barrier, then E/F tables ----
  float tv[8];
  float mx = -1e30f;
#pragma unroll
  for (int k = 0; k < 8; ++k) {
    tv[k] = tArr[bh * Nn + tid + k * 256];
    mx = fmaxf(mx, tv[k]);
  }
#pragma unroll
  for (int off = 32; off > 0; off >>= 1) mx = fmaxf(mx, __shfl_xor(mx, off));
  if (lane == 0) red[w] = mx;
  __syncthreads();
  float T = fmaxf(fmaxf(red[0], red[1]), fmaxf(red[2], red[3]));
#pragma unroll
  for (int k = 0; k < 8; ++k) {
    float dt = tv[k] - T;  // <= 0
    Ef[tid + k * 256] = (_Float16)__builtin_amdgcn_exp2f(LOG2E * dt);
    Ff[tid + k * 256] = (_Float16)__builtin_amdgcn_exp2f(0.2f * LOG2E * dt);
  }

  // per-row alpha/beta (replicated f16 pairs)
  half2v aa[4], bb[4];
#pragma unroll
  for (int t = 0; t < 4; ++t) {
    float es = sArr[bh * Nn + tile * 64 + t * 16 + m] + T;
    float al = __builtin_amdgcn_exp2f(0.8f * LOG2E * fminf(es, 0.f));
    float be = __builtin_amdgcn_exp2f(-0.8f * LOG2E * fmaxf(es, 0.f));
    _Float16 ah_ = (_Float16)al, bh_ = (_Float16)be;
    aa[t] = (half2v){ah_, ah_};
    bb[t] = (half2v){bh_, bh_};
  }
  __syncthreads();  // E/F visible to all waves

  f32x4 acc[4][2];
  f32x4 accd[4];
#pragma unroll
  for (int t = 0; t < 4; ++t) {
    acc[t][0] = (f32x4){0.f, 0.f, 0.f, 0.f};
    acc[t][1] = (f32x4){0.f, 0.f, 0.f, 0.f};
    accd[t] = (f32x4){0.f, 0.f, 0.f, 0.f};
  }
  // den via MFMA: B fragment = ones in column 0 (lanes m==0), zero elsewhere.
  half8 bden;
  {
    _Float16 v = (_Float16)((m == 0) ? 1.f : 0.f);
#pragma unroll
    for (int j = 0; j < 8; ++j) bden[j] = v;
  }

  const _Float16* wb = whT + (size_t)bh * Dd * Nn;
  const int jb0 = w * 512;
  const _Float16* wb0 = wb + (size_t)m * Nn + jb0;
  const _Float16* wb1 = wb + (size_t)(16 + m) * Nn + jb0;

  // ---- main loop: 16 steps of 32 j, depth-2 pipeline, no barriers/exp ----
  half8 B0a = *(const half8*)(wb0 + q * 8);
  half8 B1a = *(const half8*)(wb1 + q * 8);
  H8 Ea, Fa, Eb, Fb;
  Ea.h8 = *(const half8*)&Ef[jb0 + q * 8];
  Fa.h8 = *(const half8*)&Ff[jb0 + q * 8];
  half8 B0b = *(const half8*)(wb0 + 32 + q * 8);
  half8 B1b = *(const half8*)(wb1 + 32 + q * 8);
  Eb.h8 = *(const half8*)&Ef[jb0 + 32 + q * 8];
  Fb.h8 = *(const half8*)&Ff[jb0 + 32 + q * 8];

  for (int s = 0; s < 16; s += 2) {
    int j2 = ((s + 2) & 15) * 32;  // wrap: final iter's loads unused
    int j3 = ((s + 3) & 15) * 32;
    half8 nB0a = *(const half8*)(wb0 + j2 + q * 8);
    half8 nB1a = *(const half8*)(wb1 + j2 + q * 8);
    H8 nEa, nFa, nEb, nFb;
    nEa.h8 = *(const half8*)&Ef[jb0 + j2 + q * 8];
    nFa.h8 = *(const half8*)&Ff[jb0 + j2 + q * 8];
    half8 nB0b = *(const half8*)(wb0 + j3 + q * 8);
    half8 nB1b = *(const half8*)(wb1 + j3 + q * 8);
    nEb.h8 = *(const half8*)&Ef[jb0 + j3 + q * 8];
    nFb.h8 = *(const half8*)&Ff[jb0 + j3 + q * 8];

    // step s (buffers a)
#pragma unroll
    for (int t = 0; t < 4; ++t) {
      H8 P;
#pragma unroll
      for (int kk = 0; kk < 4; ++kk) {
        half2v pe = aa[t] * Ea.h2[kk];                 // v_pk_mul_f16
        half2v pf = bb[t] * Fa.h2[kk];                 // v_pk_mul_f16
        P.h2[kk] = __builtin_elementwise_max(pe, pf);  // v_pk_max_f16
      }
      acc[t][0] = __builtin_amdgcn_mfma_f32_16x16x32_f16(P.h8, B0a, acc[t][0], 0, 0, 0);
      acc[t][1] = __builtin_amdgcn_mfma_f32_16x16x32_f16(P.h8, B1a, acc[t][1], 0, 0, 0);
      accd[t]  = __builtin_amdgcn_mfma_f32_16x16x32_f16(P.h8, bden, accd[t], 0, 0, 0);
    }
    // step s+1 (buffers b)
#pragma unroll
    for (int t = 0; t < 4; ++t) {
      H8 P;
#pragma unroll
      for (int kk = 0; kk < 4; ++kk) {
        half2v pe = aa[t] * Eb.h2[kk];
        half2v pf = bb[t] * Fb.h2[kk];
        P.h2[kk] = __builtin_elementwise_max(pe, pf);
      }
      acc[t][0] = __builtin_amdgcn_mfma_f32_16x16x32_f16(P.h8, B0b, acc[t][0], 0, 0, 0);
      acc[t][1] = __builtin_amdgcn_mfma_f32_16x16x32_f16(P.h8, B1b, acc[t][1], 0, 0, 0);
      accd[t]  = __builtin_amdgcn_mfma_f32_16x16x32_f16(P.h8, bden, accd[t], 0, 0, 0);
    }
    B0a = nB0a; B1a = nB1a; Ea = nEa; Fa = nFa;
    B0b = nB0b; B1b = nB1b; Eb = nEb; Fb = nFb;
  }

  // ---- epilogue: cross-wave reduce + divide + elu + store ----
  __syncthreads();  // E/F dead; reuse smem
  float* redN = smem;                // [4][64][33]
  float* redD = smem + 4 * 64 * 33;  // [4][64]
#pragma unroll
  for (int t = 0; t < 4; ++t) {
#pragma unroll
    for (int dh = 0; dh < 2; ++dh)
#pragma unroll
      for (int r = 0; r < 4; ++r)
        redN[(w * 64 + t * 16 + q * 4 + r) * 33 + dh * 16 + m] = acc[t][dh][r];
    if (m == 0) {
#pragma unroll
      for (int r = 0; r < 4; ++r)
        redD[w * 64 + t * 16 + q * 4 + r] = accd[t][r];  // den at col-0 lanes
    }
  }
  __syncthreads();
  {
    int rl = tid >> 2, dg = (tid & 3) * 8;
    float num[8];
#pragma unroll
    for (int i = 0; i < 8; ++i)
      num[i] = redN[(0 * 64 + rl) * 33 + dg + i] + redN[(1 * 64 + rl) * 33 + dg + i] +
               redN[(2 * 64 + rl) * 33 + dg + i] + redN[(3 * 64 + rl) * 33 + dg + i];
    float dt = redD[rl] + redD[64 + rl] + redD[128 + rl] + redD[192 + rl];
    float rd = 1.0f / dt;  // den >= ~1 by construction
    float* orow = out + (size_t)(b * Nn + tile * 64 + rl) * (4 * Dd) + h * Dd + dg;
#pragma unroll
    for (int i = 0; i < 8; ++i) {
      float hv = num[i] * rd;
      num[i] = hv > 0.f ? hv : (__builtin_amdgcn_exp2f(hv * LOG2E) - 1.0f);
    }
    *(float4*)orow = make_float4(num[0], num[1], num[2], num[3]);
    *((float4*)orow + 1) = make_float4(num[4], num[5], num[6], num[7]);
  }
}

extern "C" void kernel_launch(void* const* d_in, const int* in_sizes, int n_in,
                              void* d_out, int out_size, void* d_ws, size_t ws_size,
                              hipStream_t stream) {
  const float* x = (const float*)d_in[0];   // (4,2048,128)
  const float* W = (const float*)d_in[1];   // (4,128,32)
  const float* a = (const float*)d_in[2];   // (4,64)
  float* out = (float*)d_out;               // (4,2048,128)

  float* wsf = (float*)d_ws;
  float* sArr = wsf;                          // 32768 f32
  float* tArr = sArr + 32768;                 // 32768 f32
  _Float16* whT = (_Float16*)(tArr + 32768);  // 16*32*2048 f16 = 2 MB

  k1_wh<<<dim3(512), dim3(256), 0, stream>>>(x, W, a, whT, sArr, tArr);
  k3_attn<<<dim3(512), dim3(256), 0, stream>>>(whT, sArr, tArr, out);
}